// Round 18
// baseline (2188.735 us; speedup 1.0000x reference)
//
#include <hip/hip_runtime.h>
#include <hip/hip_bf16.h>
#include <cstdint>

// ChromaticResonance R18: 32x32x16 MFMA shape.
// R17 learned: conflict counter = inherent b128 phase cost (scales exactly
// with A-read count, swizzle-invariant). R16 is issue-bound: MFMA 45% +
// VALU 39%. 32x32x16: +15% MFMA rate (2382 vs 2075 TF measured), half the
// MFMA instructions, half the A-reads, one col/lane constants. Geometry:
// 16 waves x (M=32 GEMM rows x N=32) tiles, acc = 4 x f32x16 = 64 AGPR.
// C/D map (HW-verified m74/m101): col=lane&31, row=(reg&3)+8*(reg>>2)
// +4*(lane>>5). A/B: row/col=lane&31, k=(lane>>5)*8+i.
// packed B v3: [t:16][ks:32][f:6][512] u16, f={o0h,o0l,o1h,o2h,o3h,o3l}.

typedef __bf16 bf16_t;
typedef bf16_t bf16x8 __attribute__((ext_vector_type(8)));
typedef float f32x16 __attribute__((ext_vector_type(16)));
typedef _Float16 h2_t __attribute__((ext_vector_type(2)));

#define B_ROWS 32768
#define D_DIM 512
#define N_DEPTH 7
#define BD ((size_t)B_ROWS * D_DIM)

__device__ __forceinline__ unsigned short f2b(float f) {
  bf16_t h = (bf16_t)f;
  return __builtin_bit_cast(unsigned short, h);
}
__device__ __forceinline__ float b2f(unsigned short u) {
  bf16_t h = __builtin_bit_cast(bf16_t, u);
  return (float)h;
}
__device__ __forceinline__ float fast_tanh(float x) {
  float ax = fabsf(x);
  float e = __expf(2.0f * ax);
  float t = 1.0f - 2.0f / (e + 1.0f);
  return copysignf(t, x);
}
// LDS plane: [32 rows][512 bf16], 1KB/row, XOR swizzle (row&7)<<4 (R16's).
__device__ __forceinline__ int lds_addr(int row, int byte_in_row) {
  return row * 1024 + (byte_in_row ^ ((row & 7) << 4));
}

// Prepack for 32x32x16 B-fragments: col = lane&31, k = (lane>>5)*8 + i.
// dst[t:16][ks:32][f:6][512]: t = 32-col tile, ks = K/16 step.
__global__ __launch_bounds__(256) void prepack_v3(
    const float* __restrict__ cm, const float* __restrict__ h1,
    const float* __restrict__ h2, const float* __restrict__ h3,
    const float* __restrict__ h5, unsigned short* __restrict__ dst) {
  int gid = blockIdx.x * 256 + threadIdx.x;  // 0..32767
  if (gid >= 16 * 32 * 64) return;
  int l  = gid & 63;
  int ks = (gid >> 6) & 31;
  int t  = gid >> 11;  // 0..15
  int n  = t * 32 + (l & 31);
  int k0 = ks * 16 + (l >> 5) * 8;
  unsigned short* base = dst + ((size_t)(t * 32 + ks) * 6) * 512 + l * 8;
  bf16x8 f0, f1, f2, f3, f4, f5;
#pragma unroll
  for (int i = 0; i < 8; ++i) {
    size_t idx = (size_t)(k0 + i) * D_DIM + n;
    float v0 = cm[idx] + h1[idx];
    unsigned short h0 = f2b(v0);
    f0[i] = __builtin_bit_cast(bf16_t, h0);
    f1[i] = (bf16_t)(v0 - b2f(h0));
    f2[i] = (bf16_t)h2[idx];
    f3[i] = (bf16_t)h3[idx];
    float v5 = h5[idx];
    unsigned short h5v = f2b(v5);
    f4[i] = __builtin_bit_cast(bf16_t, h5v);
    f5[i] = (bf16_t)(v5 - b2f(h5v));
  }
  *(bf16x8*)(base + 0 * 512) = f0;
  *(bf16x8*)(base + 1 * 512) = f1;
  *(bf16x8*)(base + 2 * 512) = f2;
  *(bf16x8*)(base + 3 * 512) = f3;
  *(bf16x8*)(base + 4 * 512) = f4;
  *(bf16x8*)(base + 5 * 512) = f5;
}

__global__ __launch_bounds__(1024) void resonance_kernel(
    const float* __restrict__ wr, const float* __restrict__ wi,
    const float* __restrict__ scale, const float* __restrict__ bias,
    const unsigned short* __restrict__ pre, float* __restrict__ out) {
  __shared__ unsigned short lds_hi[2][32 * 512];  // 2 x 32KB
  __shared__ unsigned short lds_lo[2][32 * 512];  // 2 x 32KB

  const int tid  = threadIdx.x;
  const int lane = tid & 63;
  const int wave = tid >> 6;   // 0..15 = ntile
  const int l31  = lane & 31;
  const int hh   = lane >> 5;  // 0..1 (k-half / row+4 select)
  const int r0   = blockIdx.x * 16;  // 16 complex rows per block

  // ---- stage initial wave into buffer 0 (GEMM rows: 0-15 re, 16-31 im) ----
#pragma unroll
  for (int it = 0; it < 2; ++it) {
    int idx = it * 1024 + tid;  // 0..2047, 8 elems each
    int row = idx >> 6;         // 0..31
    int k0  = (idx & 63) * 8;
    const float* src = (row < 16)
        ? (wr + (size_t)(r0 + row) * D_DIM + k0)
        : (wi + (size_t)(r0 + row - 16) * D_DIM + k0);
    float4 v0 = *(const float4*)(src);
    float4 v1 = *(const float4*)(src + 4);
    float v[8] = {v0.x, v0.y, v0.z, v0.w, v1.x, v1.y, v1.z, v1.w};
    bf16x8 ph, pl;
#pragma unroll
    for (int j = 0; j < 8; ++j) {
      unsigned short h = f2b(v[j]);
      ph[j] = __builtin_bit_cast(bf16_t, h);
      pl[j] = (bf16_t)(v[j] - b2f(h));
    }
    int ad = lds_addr(row, k0 * 2);
    *(bf16x8*)((char*)lds_hi[0] + ad) = ph;
    *(bf16x8*)((char*)lds_lo[0] + ad) = pl;
  }
  __syncthreads();

  float Wsum = 0.0f;
#pragma unroll
  for (int d = 0; d < N_DEPTH; ++d) Wsum += __expf(-(float)d * (1.0f / 3.0f));
  const float invW = 1.0f / Wsum;

  // per-lane column constants (one column per lane now)
  const int col = wave * 32 + l31;
  const float sclv = scale[col];
  const float biav = bias[col];
  const float damp = 0.1f / (1.0f + __expf(3.0f * (float)col * (1.0f / 511.0f)));

  h2_t oacc[8];  // [j] packed fp16 (re, im) output accumulator
#pragma unroll
  for (int j = 0; j < 8; ++j) oacc[j] = (h2_t){(_Float16)0.f, (_Float16)0.f};

  int cur = 0;
  for (int depth = 0; depth < N_DEPTH; ++depth) {
    const float wd = __expf(-(float)depth * (1.0f / 3.0f)) * invW;
    const float fac = __expf(-damp * (float)depth);
    const char* Ahi = (const char*)lds_hi[cur];
    const char* Alo = (const char*)lds_lo[cur];
    char* Nhi = (char*)lds_hi[cur ^ 1];
    char* Nlo = (char*)lds_lo[cur ^ 1];

    f32x16 a0 = (f32x16)(0.f), a1 = (f32x16)(0.f);
    f32x16 a2 = (f32x16)(0.f), a3 = (f32x16)(0.f);

    const unsigned short* bb = pre + ((size_t)(wave * 32) * 6 + 3) * 512 + lane * 8;
#pragma unroll 2
    for (int ks = 0; ks < 32; ++ks) {
      int ad = lds_addr(l31, ks * 32 + hh * 16);
      bf16x8 ah = *(const bf16x8*)(Ahi + ad);
      bf16x8 al = *(const bf16x8*)(Alo + ad);
      bf16x8 b0h = *(const bf16x8*)(bb - 1536);
      bf16x8 b0l = *(const bf16x8*)(bb - 1024);
      bf16x8 b1h = *(const bf16x8*)(bb - 512);
      bf16x8 b2h = *(const bf16x8*)(bb);
      bf16x8 b3h = *(const bf16x8*)(bb + 512);
      bf16x8 b3l = *(const bf16x8*)(bb + 1024);
      bb += 3072;
      a0 = __builtin_amdgcn_mfma_f32_32x32x16_bf16(ah, b0h, a0, 0, 0, 0);
      a0 = __builtin_amdgcn_mfma_f32_32x32x16_bf16(al, b0h, a0, 0, 0, 0);
      a0 = __builtin_amdgcn_mfma_f32_32x32x16_bf16(ah, b0l, a0, 0, 0, 0);
      a1 = __builtin_amdgcn_mfma_f32_32x32x16_bf16(ah, b1h, a1, 0, 0, 0);
      a2 = __builtin_amdgcn_mfma_f32_32x32x16_bf16(ah, b2h, a2, 0, 0, 0);
      a3 = __builtin_amdgcn_mfma_f32_32x32x16_bf16(ah, b3h, a3, 0, 0, 0);
      a3 = __builtin_amdgcn_mfma_f32_32x32x16_bf16(al, b3h, a3, 0, 0, 0);
      a3 = __builtin_amdgcn_mfma_f32_32x32x16_bf16(ah, b3l, a3, 0, 0, 0);
    }

    // ---- elementwise: 8 complex elems/lane: crow=(j&3)+8*(j>>2)+4*hh ----
#pragma unroll
    for (int j = 0; j < 8; ++j) {
      const int crow = (j & 3) + 8 * (j >> 2) + 4 * hh;  // complex row 0..15
      float lr = a0[j],  li = a0[j + 8];   // coupling + h1
      float re2 = a1[j], im2 = a1[j + 8];
      float ar = 0.25f * (re2 * re2 + im2 * im2);  // h2 real
      float re3 = a2[j], im3 = a2[j + 8];
      float m3 = re3 * re3 + im3 * im3;
      ar += 0.111111111f * m3 * re3;               // h3
      float ai = 0.111111111f * m3 * im3;
      float re5 = a3[j], im5 = a3[j + 8];
      float m5 = re5 * re5 + im5 * im5;
      {
        // h5 = |hw|^(1/5) exp(i 5 ang) / 25
        float m5c = fmaxf(m5, 1e-36f);
        float inv = rsqrtf(m5c);
        float ur = re5 * inv, ui = im5 * inv;
        float u2r = ur * ur - ui * ui,     u2i = 2.0f * ur * ui;
        float u4r = u2r * u2r - u2i * u2i, u4i = 2.0f * u2r * u2i;
        float u5r = u4r * ur - u4i * ui,   u5i = u4r * ui + u4i * ur;
        float mag = __expf(0.1f * __logf(m5c));
        float msk = (m5 > 1e-36f) ? 0.04f : 0.0f;
        ar += msk * mag * u5r;
        ai += msk * mag * u5i;
      }
      float ir = lr + ar, ii = li + ai;
      const int colb = col * 2;
      const int ar_ = lds_addr(crow, colb);
      const int ai_ = lds_addr(crow + 16, colb);
      if (depth > 0) {  // interference: old chamber = cur buffer (hi+lo)
        ir += b2f(*(const unsigned short*)(Ahi + ar_))
            + b2f(*(const unsigned short*)(Alo + ar_));
        ii += b2f(*(const unsigned short*)(Ahi + ai_))
            + b2f(*(const unsigned short*)(Alo + ai_));
      }
      float cre = fast_tanh(ir * sclv + biav) * fac;
      float cim = fast_tanh(ii * sclv + biav) * fac;
      oacc[j] += (h2_t){(_Float16)(wd * cre), (_Float16)(wd * cim)};
      if (depth < N_DEPTH - 1) {  // state into next buffer
        unsigned short hr = f2b(cre);
        unsigned short hi = f2b(cim);
        *(unsigned short*)(Nhi + ar_) = hr;
        *(unsigned short*)(Nlo + ar_) = f2b(cre - b2f(hr));
        *(unsigned short*)(Nhi + ai_) = hi;
        *(unsigned short*)(Nlo + ai_) = f2b(cim - b2f(hi));
      }
    }
    __syncthreads();  // next buffer fully written before next depth reads it
    cur ^= 1;
  }

  // ---- write weighted sum ----
#pragma unroll
  for (int j = 0; j < 8; ++j) {
    const int crow = (j & 3) + 8 * (j >> 2) + 4 * hh;
    size_t base = (size_t)(r0 + crow) * D_DIM + col;
    out[base] = (float)oacc[j][0];
    out[BD + base] = (float)oacc[j][1];
  }
}

extern "C" void kernel_launch(void* const* d_in, const int* in_sizes, int n_in,
                              void* d_out, int out_size, void* d_ws, size_t ws_size,
                              hipStream_t stream) {
  const float* wr = (const float*)d_in[0];
  const float* wi = (const float*)d_in[1];
  const float* cm = (const float*)d_in[2];
  const float* h1 = (const float*)d_in[3];
  const float* h2 = (const float*)d_in[4];
  const float* h3 = (const float*)d_in[5];
  const float* h5 = (const float*)d_in[6];
  const float* sc = (const float*)d_in[7];
  const float* bi = (const float*)d_in[8];
  unsigned short* pre = (unsigned short*)d_ws;  // 3MB packed B
  float* out = (float*)d_out;

  hipLaunchKernelGGL(prepack_v3, dim3(128), dim3(256), 0, stream,
                     cm, h1, h2, h3, h5, pre);
  hipLaunchKernelGGL(resonance_kernel, dim3(B_ROWS / 16), dim3(1024), 0, stream,
                     wr, wi, sc, bi, pre, out);
}

// Round 19
// 1945.589 us; speedup vs baseline: 1.1250x; 1.1250x over previous
//
#include <hip/hip_runtime.h>
#include <hip/hip_bf16.h>
#include <cstdint>

// ChromaticResonance R19: R16 exactly + s_setprio(1) around the MFMA ks-loop
// (T5). R18's 32x32 shape reverted (longer MFMA latency, fewer chains ->
// MfmaUtil fell). Five configs plateau ~1950-2000us; R16 best at 1946.
// setprio is the last zero-risk scheduling lever: R16 has 2 independent
// blocks/CU + barrier-offset waves (role diversity, unlike m190 lockstep).
// Math bitwise R16 -> absmax 0.01757812.
// packed B: [t:32][ks:16][f:6][512] u16, f = {o0h, o0l, o1h, o2h, o3h, o3l}.

typedef __bf16 bf16_t;
typedef bf16_t bf16x8 __attribute__((ext_vector_type(8)));
typedef float f32x4 __attribute__((ext_vector_type(4)));
typedef _Float16 h2_t __attribute__((ext_vector_type(2)));

#define B_ROWS 32768
#define D_DIM 512
#define N_DEPTH 7
#define BD ((size_t)B_ROWS * D_DIM)

__device__ __forceinline__ unsigned short f2b(float f) {
  bf16_t h = (bf16_t)f;
  return __builtin_bit_cast(unsigned short, h);
}
__device__ __forceinline__ float b2f(unsigned short u) {
  bf16_t h = __builtin_bit_cast(bf16_t, u);
  return (float)h;
}
__device__ __forceinline__ float fast_tanh(float x) {
  float ax = fabsf(x);
  float e = __expf(2.0f * ax);
  float t = 1.0f - 2.0f / (e + 1.0f);
  return copysignf(t, x);
}
// LDS plane: [32 rows][512 bf16], 1KB/row, XOR swizzle (row&7)<<4.
__device__ __forceinline__ int lds_addr(int row, int byte_in_row) {
  return row * 1024 + (byte_in_row ^ ((row & 7) << 4));
}

// B-fragment map (mfma_f32_16x16x32_bf16): col = lane&15, k = (lane>>4)*8+i.
__global__ __launch_bounds__(256) void prepack_v2(
    const float* __restrict__ cm, const float* __restrict__ h1,
    const float* __restrict__ h2, const float* __restrict__ h3,
    const float* __restrict__ h5, unsigned short* __restrict__ dst) {
  int gid = blockIdx.x * 256 + threadIdx.x;  // 0..32767
  if (gid >= 32 * 16 * 64) return;
  int l  = gid & 63;
  int ks = (gid >> 6) & 15;
  int t  = gid >> 10;
  int n  = t * 16 + (l & 15);
  int k0 = ks * 32 + (l >> 4) * 8;
  unsigned short* base = dst + ((size_t)(t * 16 + ks) * 6) * 512 + l * 8;
  bf16x8 f0, f1, f2, f3, f4, f5;
#pragma unroll
  for (int i = 0; i < 8; ++i) {
    size_t idx = (size_t)(k0 + i) * D_DIM + n;
    float v0 = cm[idx] + h1[idx];
    unsigned short h0 = f2b(v0);
    f0[i] = __builtin_bit_cast(bf16_t, h0);
    f1[i] = (bf16_t)(v0 - b2f(h0));
    f2[i] = (bf16_t)h2[idx];
    f3[i] = (bf16_t)h3[idx];
    float v5 = h5[idx];
    unsigned short h5v = f2b(v5);
    f4[i] = __builtin_bit_cast(bf16_t, h5v);
    f5[i] = (bf16_t)(v5 - b2f(h5v));
  }
  *(bf16x8*)(base + 0 * 512) = f0;
  *(bf16x8*)(base + 1 * 512) = f1;
  *(bf16x8*)(base + 2 * 512) = f2;
  *(bf16x8*)(base + 3 * 512) = f3;
  *(bf16x8*)(base + 4 * 512) = f4;
  *(bf16x8*)(base + 5 * 512) = f5;
}

__global__ __launch_bounds__(1024) void resonance_kernel(
    const float* __restrict__ wr, const float* __restrict__ wi,
    const float* __restrict__ scale, const float* __restrict__ bias,
    const unsigned short* __restrict__ pre, float* __restrict__ out) {
  __shared__ unsigned short lds_hi[2][32 * 512];  // 2 x 32KB
  __shared__ unsigned short lds_lo[2][32 * 512];  // 2 x 32KB

  const int tid  = threadIdx.x;
  const int lane = tid & 63;
  const int wave = tid >> 6;   // 0..15
  const int ln15 = lane & 15;
  const int lg   = lane >> 4;  // 0..3
  const int r0   = blockIdx.x * 16;  // 16 complex rows per block

  // ---- stage initial wave into buffer 0 (GEMM rows: 0-15 re, 16-31 im) ----
#pragma unroll
  for (int it = 0; it < 2; ++it) {
    int idx = it * 1024 + tid;  // 0..2047, 8 elems each
    int row = idx >> 6;         // 0..31
    int k0  = (idx & 63) * 8;
    const float* src = (row < 16)
        ? (wr + (size_t)(r0 + row) * D_DIM + k0)
        : (wi + (size_t)(r0 + row - 16) * D_DIM + k0);
    float4 v0 = *(const float4*)(src);
    float4 v1 = *(const float4*)(src + 4);
    float v[8] = {v0.x, v0.y, v0.z, v0.w, v1.x, v1.y, v1.z, v1.w};
    bf16x8 ph, pl;
#pragma unroll
    for (int j = 0; j < 8; ++j) {
      unsigned short h = f2b(v[j]);
      ph[j] = __builtin_bit_cast(bf16_t, h);
      pl[j] = (bf16_t)(v[j] - b2f(h));
    }
    int ad = lds_addr(row, k0 * 2);
    *(bf16x8*)((char*)lds_hi[0] + ad) = ph;
    *(bf16x8*)((char*)lds_lo[0] + ad) = pl;
  }
  __syncthreads();

  float Wsum = 0.0f;
#pragma unroll
  for (int d = 0; d < N_DEPTH; ++d) Wsum += __expf(-(float)d * (1.0f / 3.0f));
  const float invW = 1.0f / Wsum;

  h2_t oacc[2][4];  // [chunk][r] packed fp16 (re, im) output accumulator
#pragma unroll
  for (int c = 0; c < 2; ++c)
#pragma unroll
    for (int r = 0; r < 4; ++r) oacc[c][r] = (h2_t){(_Float16)0.f, (_Float16)0.f};

  int cur = 0;
  for (int depth = 0; depth < N_DEPTH; ++depth) {
    const float wd = __expf(-(float)depth * (1.0f / 3.0f)) * invW;
    const char* Ahi = (const char*)lds_hi[cur];
    const char* Alo = (const char*)lds_lo[cur];
    char* Nhi = (char*)lds_hi[cur ^ 1];
    char* Nlo = (char*)lds_lo[cur ^ 1];

#pragma unroll
    for (int c = 0; c < 2; ++c) {
      const int t = c * 16 + wave;  // ntile 0..31
      f32x4 acc0[2], acc1[2], acc2[2], acc3[2];  // [mt] 32 AGPR
#pragma unroll
      for (int mt = 0; mt < 2; ++mt) {
        acc0[mt] = (f32x4){0.f, 0.f, 0.f, 0.f};
        acc1[mt] = (f32x4){0.f, 0.f, 0.f, 0.f};
        acc2[mt] = (f32x4){0.f, 0.f, 0.f, 0.f};
        acc3[mt] = (f32x4){0.f, 0.f, 0.f, 0.f};
      }

      const unsigned short* bb = pre + ((size_t)(t * 16) * 6 + 3) * 512 + lane * 8;
      __builtin_amdgcn_s_setprio(1);  // favor this wave while MFMA-dense
#pragma unroll 2
      for (int ks = 0; ks < 16; ++ks) {
        bf16x8 ah[2], al[2];
#pragma unroll
        for (int mt = 0; mt < 2; ++mt) {
          int ad = lds_addr(mt * 16 + ln15, ks * 64 + lg * 16);
          ah[mt] = *(const bf16x8*)(Ahi + ad);
          al[mt] = *(const bf16x8*)(Alo + ad);
        }
        bf16x8 b0h = *(const bf16x8*)(bb - 1536);
        bf16x8 b0l = *(const bf16x8*)(bb - 1024);
        bf16x8 b1h = *(const bf16x8*)(bb - 512);
        bf16x8 b2h = *(const bf16x8*)(bb);
        bf16x8 b3h = *(const bf16x8*)(bb + 512);
        bf16x8 b3l = *(const bf16x8*)(bb + 1024);
        bb += 3072;
#pragma unroll
        for (int mt = 0; mt < 2; ++mt) {
          acc0[mt] = __builtin_amdgcn_mfma_f32_16x16x32_bf16(ah[mt], b0h, acc0[mt], 0, 0, 0);
          acc0[mt] = __builtin_amdgcn_mfma_f32_16x16x32_bf16(al[mt], b0h, acc0[mt], 0, 0, 0);
          acc0[mt] = __builtin_amdgcn_mfma_f32_16x16x32_bf16(ah[mt], b0l, acc0[mt], 0, 0, 0);
          acc1[mt] = __builtin_amdgcn_mfma_f32_16x16x32_bf16(ah[mt], b1h, acc1[mt], 0, 0, 0);
          acc2[mt] = __builtin_amdgcn_mfma_f32_16x16x32_bf16(ah[mt], b2h, acc2[mt], 0, 0, 0);
          acc3[mt] = __builtin_amdgcn_mfma_f32_16x16x32_bf16(ah[mt], b3h, acc3[mt], 0, 0, 0);
          acc3[mt] = __builtin_amdgcn_mfma_f32_16x16x32_bf16(al[mt], b3h, acc3[mt], 0, 0, 0);
          acc3[mt] = __builtin_amdgcn_mfma_f32_16x16x32_bf16(ah[mt], b3l, acc3[mt], 0, 0, 0);
        }
      }
      __builtin_amdgcn_s_setprio(0);  // back to normal for elementwise

      // ---- elementwise: complex rows lg*4+r, col t*16+ln15 ----
      const int col = t * 16 + ln15;
      const float sclv = scale[col];
      const float biav = bias[col];
      const float damp = 0.1f / (1.0f + __expf(3.0f * (float)col * (1.0f / 511.0f)));
      const float fac  = __expf(-damp * (float)depth);
#pragma unroll
      for (int r = 0; r < 4; ++r) {
        const int brow = lg * 4 + r;  // complex row 0..15
        float lr = acc0[0][r],  li = acc0[1][r];   // coupling + h1
        float re2 = acc1[0][r], im2 = acc1[1][r];
        float ar = 0.25f * (re2 * re2 + im2 * im2);  // h2 real
        float re3 = acc2[0][r], im3 = acc2[1][r];
        float m3 = re3 * re3 + im3 * im3;
        ar += 0.111111111f * m3 * re3;               // h3
        float ai = 0.111111111f * m3 * im3;
        float re5 = acc3[0][r], im5 = acc3[1][r];
        float m5 = re5 * re5 + im5 * im5;
        {
          // h5 = |hw|^(1/5) exp(i 5 ang) / 25
          float m5c = fmaxf(m5, 1e-36f);
          float inv = rsqrtf(m5c);
          float ur = re5 * inv, ui = im5 * inv;
          float u2r = ur * ur - ui * ui,     u2i = 2.0f * ur * ui;
          float u4r = u2r * u2r - u2i * u2i, u4i = 2.0f * u2r * u2i;
          float u5r = u4r * ur - u4i * ui,   u5i = u4r * ui + u4i * ur;
          float mag = __expf(0.1f * __logf(m5c));
          float msk = (m5 > 1e-36f) ? 0.04f : 0.0f;
          ar += msk * mag * u5r;
          ai += msk * mag * u5i;
        }
        float ir = lr + ar, ii = li + ai;
        const int colb = col * 2;
        const int ar_ = lds_addr(brow, colb);
        const int ai_ = lds_addr(brow + 16, colb);
        if (depth > 0) {  // interference: old chamber = cur buffer (hi+lo)
          ir += b2f(*(const unsigned short*)(Ahi + ar_))
              + b2f(*(const unsigned short*)(Alo + ar_));
          ii += b2f(*(const unsigned short*)(Ahi + ai_))
              + b2f(*(const unsigned short*)(Alo + ai_));
        }
        float cre = fast_tanh(ir * sclv + biav) * fac;
        float cim = fast_tanh(ii * sclv + biav) * fac;
        oacc[c][r] += (h2_t){(_Float16)(wd * cre), (_Float16)(wd * cim)};
        if (depth < N_DEPTH - 1) {  // state into next buffer
          unsigned short hr = f2b(cre);
          unsigned short hi = f2b(cim);
          *(unsigned short*)(Nhi + ar_) = hr;
          *(unsigned short*)(Nlo + ar_) = f2b(cre - b2f(hr));
          *(unsigned short*)(Nhi + ai_) = hi;
          *(unsigned short*)(Nlo + ai_) = f2b(cim - b2f(hi));
        }
      }
    }
    __syncthreads();  // next buffer fully written before next depth reads it
    cur ^= 1;
  }

  // ---- write weighted sum ----
#pragma unroll
  for (int c = 0; c < 2; ++c) {
    const int col = (c * 16 + wave) * 16 + ln15;
#pragma unroll
    for (int r = 0; r < 4; ++r) {
      int brow = lg * 4 + r;
      size_t base = (size_t)(r0 + brow) * D_DIM + col;
      out[base] = (float)oacc[c][r][0];
      out[BD + base] = (float)oacc[c][r][1];
    }
  }
}

extern "C" void kernel_launch(void* const* d_in, const int* in_sizes, int n_in,
                              void* d_out, int out_size, void* d_ws, size_t ws_size,
                              hipStream_t stream) {
  const float* wr = (const float*)d_in[0];
  const float* wi = (const float*)d_in[1];
  const float* cm = (const float*)d_in[2];
  const float* h1 = (const float*)d_in[3];
  const float* h2 = (const float*)d_in[4];
  const float* h3 = (const float*)d_in[5];
  const float* h5 = (const float*)d_in[6];
  const float* sc = (const float*)d_in[7];
  const float* bi = (const float*)d_in[8];
  unsigned short* pre = (unsigned short*)d_ws;  // 3MB packed B
  float* out = (float*)d_out;

  hipLaunchKernelGGL(prepack_v2, dim3(128), dim3(256), 0, stream,
                     cm, h1, h2, h3, h5, pre);
  hipLaunchKernelGGL(resonance_kernel, dim3(B_ROWS / 16), dim3(1024), 0, stream,
                     wr, wi, sc, bi, pre, out);
}